// Round 1
// baseline (1162.248 us; speedup 1.0000x reference)
//
#include <hip/hip_runtime.h>

typedef _Float16 f16;
typedef _Float16 f16x8 __attribute__((ext_vector_type(8)));
typedef float f32x4 __attribute__((ext_vector_type(4)));

#define B_ 512
#define L_ 512
#define Cc_ 64
#define Ct_ 16
#define Co_ 8
#define H_ 128
#define IN_ 88
#define KP 96       // padded K for MFMA
#define G3 384      // 3*H

// ---------------- K0: pad+convert W_ih (384x88 f32) -> (384x96 f16) ----------------
__global__ void k_prep_wih(const float* __restrict__ Wih, f16* __restrict__ WihH) {
    int idx = blockIdx.x * 256 + threadIdx.x;   // 384*96 = 36864 total
    if (idx >= G3 * KP) return;
    int n = idx / KP, k = idx % KP;
    WihH[idx] = (k < IN_) ? (f16)Wih[n * IN_ + k] : (f16)0.f;
}

// ---------------- K1: time-norm (mean/var over L per (b,ch)) + concat -> f16 (B*L x 96) ----
__global__ __launch_bounds__(256) void k_norm(
        const float* __restrict__ cov, const float* __restrict__ tr, const float* __restrict__ oc,
        const float* __restrict__ g_t, const float* __restrict__ bt,
        const float* __restrict__ g_o, const float* __restrict__ bo,
        const float* __restrict__ g_c, const float* __restrict__ bc,
        f16* __restrict__ inpH) {
    int b = blockIdx.x, t = threadIdx.x;
    __shared__ float ps[256], ps2[256];
    __shared__ float sc[88], sh[88];   // concat order: t[0:16), o[16:24), c[24:88)

    { // covariates, C=64, 4 l-groups
        int c = t & 63, lg = t >> 6;
        const float* p = cov + (size_t)b * L_ * Cc_ + c;
        float s = 0.f, s2 = 0.f;
        for (int i = lg; i < L_; i += 4) { float v = p[(size_t)i * Cc_]; s += v; s2 += v * v; }
        ps[t] = s; ps2[t] = s2; __syncthreads();
        if (t < 64) {
            float S = 0.f, S2 = 0.f;
            for (int g = 0; g < 4; g++) { S += ps[t + 64 * g]; S2 += ps2[t + 64 * g]; }
            float m = S * (1.f / L_), v = S2 * (1.f / L_) - m * m;
            float inv = rsqrtf(v + 1e-5f);
            float gg = g_c[t] * inv;
            sc[24 + t] = gg; sh[24 + t] = bc[t] - m * gg;
        }
        __syncthreads();
    }
    { // treatments, C=16, 16 l-groups
        int c = t & 15, lg = t >> 4;
        const float* p = tr + (size_t)b * L_ * Ct_ + c;
        float s = 0.f, s2 = 0.f;
        for (int i = lg; i < L_; i += 16) { float v = p[(size_t)i * Ct_]; s += v; s2 += v * v; }
        ps[t] = s; ps2[t] = s2; __syncthreads();
        if (t < 16) {
            float S = 0.f, S2 = 0.f;
            for (int g = 0; g < 16; g++) { S += ps[t + 16 * g]; S2 += ps2[t + 16 * g]; }
            float m = S * (1.f / L_), v = S2 * (1.f / L_) - m * m;
            float inv = rsqrtf(v + 1e-5f);
            float gg = g_t[t] * inv;
            sc[t] = gg; sh[t] = bt[t] - m * gg;
        }
        __syncthreads();
    }
    { // outcomes, C=8, 32 l-groups
        int c = t & 7, lg = t >> 3;
        const float* p = oc + (size_t)b * L_ * Co_ + c;
        float s = 0.f, s2 = 0.f;
        for (int i = lg; i < L_; i += 32) { float v = p[(size_t)i * Co_]; s += v; s2 += v * v; }
        ps[t] = s; ps2[t] = s2; __syncthreads();
        if (t < 8) {
            float S = 0.f, S2 = 0.f;
            for (int g = 0; g < 32; g++) { S += ps[t + 8 * g]; S2 += ps2[t + 8 * g]; }
            float m = S * (1.f / L_), v = S2 * (1.f / L_) - m * m;
            float inv = rsqrtf(v + 1e-5f);
            float gg = g_o[t] * inv;
            sc[16 + t] = gg; sh[16 + t] = bo[t] - m * gg;
        }
        __syncthreads();
    }
    // phase B: normalize + concat + pad, write f16
    f16* outp = inpH + (size_t)b * L_ * KP;
    for (int idx = t; idx < L_ * KP; idx += 256) {
        int l = idx / KP, cc = idx % KP;   // constants -> magic mul
        float y = 0.f;
        if (cc < 88) {
            float x;
            if (cc < 16)      x = tr[((size_t)b * L_ + l) * Ct_ + cc];
            else if (cc < 24) x = oc[((size_t)b * L_ + l) * Co_ + (cc - 16)];
            else              x = cov[((size_t)b * L_ + l) * Cc_ + (cc - 24)];
            y = x * sc[cc] + sh[cc];
        }
        outp[idx] = (f16)y;
    }
}

// ---------------- K2: gi = inp @ W_ih^T + b_ih, f16 MFMA, output f16 (M x 384) ----------
// Block: 256 thr = 4 waves; wave handles 16 rows x all 384 cols, K=96 (3 mfma k-steps).
// A/B fragment layout (16x16x32): elem row/col = lane&15, k = (lane>>4)*8 + j.
// D layout: col = lane&15, row = (lane>>4)*4 + reg.
__global__ __launch_bounds__(256) void k_gemm(
        const f16* __restrict__ A, const f16* __restrict__ W,
        const float* __restrict__ bih, f16* __restrict__ gi) {
    int lane = threadIdx.x & 63, wave = threadIdx.x >> 6;
    int m0 = blockIdx.x * 64 + wave * 16;
    int r = lane & 15, q = lane >> 4;

    const f16* ap = A + (size_t)(m0 + r) * KP + q * 8;
    f16x8 a0 = *(const f16x8*)(ap);
    f16x8 a1 = *(const f16x8*)(ap + 32);
    f16x8 a2 = *(const f16x8*)(ap + 64);

    for (int n0 = 0; n0 < 24; n0++) {
        const f16* bp = W + (size_t)(n0 * 16 + r) * KP + q * 8;
        f16x8 b0 = *(const f16x8*)(bp);
        f16x8 b1 = *(const f16x8*)(bp + 32);
        f16x8 b2 = *(const f16x8*)(bp + 64);
        f32x4 acc = {0.f, 0.f, 0.f, 0.f};
        acc = __builtin_amdgcn_mfma_f32_16x16x32_f16(a0, b0, acc, 0, 0, 0);
        acc = __builtin_amdgcn_mfma_f32_16x16x32_f16(a1, b1, acc, 0, 0, 0);
        acc = __builtin_amdgcn_mfma_f32_16x16x32_f16(a2, b2, acc, 0, 0, 0);
        int n = n0 * 16 + r;
        float bias = bih[n];
        f16* gp = gi + (size_t)(m0 + q * 4) * G3 + n;
        #pragma unroll
        for (int e = 0; e < 4; e++)
            gp[(size_t)e * G3] = (f16)(acc[e] + bias);
    }
}

// ---------------- K3: GRU scan. One block = one batch row. 384 threads (6 waves). --------
// Thread t owns W_hh row t in 128 VGPRs (f32). h broadcast via LDS (float4 same-addr reads).
__global__ __launch_bounds__(384) void k_scan(
        const f16* __restrict__ gi, const float* __restrict__ Whh, const float* __restrict__ bhh,
        float* __restrict__ outA, float* __restrict__ outB, int rowBase) {
    int t = threadIdx.x;
    int lrow = blockIdx.x;
    int row = rowBase + lrow;

    __shared__ __align__(16) float hS[H_];
    __shared__ float preRZ[256];
    __shared__ float hnS[H_];
    __shared__ float ginS[H_];

    // persistent W_hh row in registers
    float wf[H_];
    {
        const f32x4* wp = (const f32x4*)(Whh + (size_t)t * H_);
        #pragma unroll
        for (int qq = 0; qq < 32; qq++) {
            f32x4 wv = wp[qq];
            wf[4 * qq + 0] = wv[0]; wf[4 * qq + 1] = wv[1];
            wf[4 * qq + 2] = wv[2]; wf[4 * qq + 3] = wv[3];
        }
    }
    float bh = bhh[t];
    if (t < H_) hS[t] = 0.f;

    const f16* gp = gi + (size_t)lrow * L_ * G3 + t;
    f16 gcur = gp[0];
    __syncthreads();

    for (int l = 0; l < L_; l++) {
        // phase 1: gh[t] = dot(W_hh[t,:], h) + b_hh[t]   (h reads are LDS broadcasts)
        const f32x4* hv4 = (const f32x4*)hS;
        float a0 = 0.f, a1 = 0.f, a2 = 0.f, a3 = 0.f;
        #pragma unroll
        for (int j = 0; j < 32; j += 4) {
            f32x4 h0 = hv4[j + 0], h1 = hv4[j + 1], h2 = hv4[j + 2], h3 = hv4[j + 3];
            a0 = fmaf(wf[4*j + 0],  h0[0], a0); a0 = fmaf(wf[4*j + 1],  h0[1], a0);
            a0 = fmaf(wf[4*j + 2],  h0[2], a0); a0 = fmaf(wf[4*j + 3],  h0[3], a0);
            a1 = fmaf(wf[4*j + 4],  h1[0], a1); a1 = fmaf(wf[4*j + 5],  h1[1], a1);
            a1 = fmaf(wf[4*j + 6],  h1[2], a1); a1 = fmaf(wf[4*j + 7],  h1[3], a1);
            a2 = fmaf(wf[4*j + 8],  h2[0], a2); a2 = fmaf(wf[4*j + 9],  h2[1], a2);
            a2 = fmaf(wf[4*j + 10], h2[2], a2); a2 = fmaf(wf[4*j + 11], h2[3], a2);
            a3 = fmaf(wf[4*j + 12], h3[0], a3); a3 = fmaf(wf[4*j + 13], h3[1], a3);
            a3 = fmaf(wf[4*j + 14], h3[2], a3); a3 = fmaf(wf[4*j + 15], h3[3], a3);
        }
        float gh = (a0 + a1) + (a2 + a3) + bh;
        float gvi = (float)gcur;
        if (t < 256) { preRZ[t] = gh + gvi; }
        else         { hnS[t - 256] = gh; ginS[t - 256] = gvi; }  // keep i_n, h_n separate (r scales only h_n)
        if (l + 1 < L_) gcur = gp[(size_t)(l + 1) * G3];          // prefetch next step's gi
        __syncthreads();

        // phase 2: gates + state update + output store (threads 0..127)
        if (t < H_) {
            float rg = 1.f / (1.f + __expf(-preRZ[t]));
            float zg = 1.f / (1.f + __expf(-preRZ[128 + t]));
            float e  = __expf(-2.f * (ginS[t] + rg * hnS[t]));
            float ng = 2.f / (1.f + e) - 1.f;                     // tanh, NaN-safe
            float hnew = (1.f - zg) * ng + zg * hS[t];
            hS[t] = hnew;
            size_t o = (size_t)row * L_ + l;
            if (t < Co_) outA[o * Co_ + t] = hnew;
            else         outB[o * (H_ - Co_) + (t - Co_)] = hnew;
        }
        __syncthreads();
    }
}

// ---------------- launch ----------------
extern "C" void kernel_launch(void* const* d_in, const int* in_sizes, int n_in,
                              void* d_out, int out_size, void* d_ws, size_t ws_size,
                              hipStream_t stream) {
    (void)in_sizes; (void)n_in;
    const float* cov = (const float*)d_in[0];
    const float* tr  = (const float*)d_in[1];
    const float* oc  = (const float*)d_in[2];
    const float* Wih = (const float*)d_in[3];
    const float* Whh = (const float*)d_in[4];
    const float* bih = (const float*)d_in[5];
    const float* bhh = (const float*)d_in[6];
    const float* g_t = (const float*)d_in[7];
    const float* bt  = (const float*)d_in[8];
    const float* g_o = (const float*)d_in[9];
    const float* bo  = (const float*)d_in[10];
    const float* g_c = (const float*)d_in[11];
    const float* bc  = (const float*)d_in[12];

    float* outA = (float*)d_out;
    float* outB = (float*)d_out + (size_t)B_ * L_ * Co_;

    // workspace layout: [WihH f16 384x96 | pad to 128KB | giH f16 (M_split x 384)]
    f16* WihH = (f16*)d_ws;
    f16* giH  = (f16*)((char*)d_ws + 131072);

    // normalized f16 input lives at the TOP of d_out (dead before outputs reach it)
    size_t outBytes = (size_t)out_size * 4;
    size_t ihBytes  = (size_t)B_ * L_ * KP * 2;   // 50.3 MB
    f16* inpH = (f16*)((char*)d_out + (outBytes - ihBytes));

    // pick batch split so gi fits in ws
    int S = 8;
    const int cand[4] = {1, 2, 4, 8};
    for (int i = 0; i < 4; i++) {
        size_t need = 131072 + ((size_t)B_ / cand[i]) * L_ * G3 * 2;
        if (need <= ws_size) { S = cand[i]; break; }
    }
    int Bs = B_ / S;

    k_prep_wih<<<dim3(144), dim3(256), 0, stream>>>(Wih, WihH);
    k_norm<<<dim3(B_), dim3(256), 0, stream>>>(cov, tr, oc, g_t, bt, g_o, bo, g_c, bc, inpH);

    for (int s = 0; s < S; s++) {
        const f16* Asub = inpH + (size_t)s * Bs * L_ * KP;
        int Msub = Bs * L_;
        k_gemm<<<dim3(Msub / 64), dim3(256), 0, stream>>>(Asub, WihH, bih, giH);
        k_scan<<<dim3(Bs), dim3(384), 0, stream>>>(giH, Whh, bhh, outA, outB, s * Bs);
    }
}

// Round 2
// 928.489 us; speedup vs baseline: 1.2518x; 1.2518x over previous
//
#include <hip/hip_runtime.h>

typedef _Float16 f16;
typedef _Float16 f16x8 __attribute__((ext_vector_type(8)));
typedef _Float16 f16x4 __attribute__((ext_vector_type(4)));
typedef float f32x4 __attribute__((ext_vector_type(4)));

#define B_ 512
#define L_ 512
#define Cc_ 64
#define Ct_ 16
#define Co_ 8
#define H_ 128
#define IN_ 88
#define KP 96       // padded K for MFMA
#define G3 384      // 3*H
#define R_ 16       // batch rows per scan block

// ---------------- K0: pad+convert W_ih (384x88 f32) -> (384x96 f16) ----------------
__global__ void k_prep_wih(const float* __restrict__ Wih, f16* __restrict__ WihH) {
    int idx = blockIdx.x * 256 + threadIdx.x;   // 384*96 = 36864 total
    if (idx >= G3 * KP) return;
    int n = idx / KP, k = idx % KP;
    WihH[idx] = (k < IN_) ? (f16)Wih[n * IN_ + k] : (f16)0.f;
}

// ---------------- K1: time-norm (mean/var over L per (b,ch)) + concat -> f16 (B*L x 96) ----
__global__ __launch_bounds__(256) void k_norm(
        const float* __restrict__ cov, const float* __restrict__ tr, const float* __restrict__ oc,
        const float* __restrict__ g_t, const float* __restrict__ bt,
        const float* __restrict__ g_o, const float* __restrict__ bo,
        const float* __restrict__ g_c, const float* __restrict__ bc,
        f16* __restrict__ inpH) {
    int b = blockIdx.x, t = threadIdx.x;
    __shared__ float ps[256], ps2[256];
    __shared__ float sc[88], sh[88];   // concat order: t[0:16), o[16:24), c[24:88)

    { // covariates, C=64, 4 l-groups
        int c = t & 63, lg = t >> 6;
        const float* p = cov + (size_t)b * L_ * Cc_ + c;
        float s = 0.f, s2 = 0.f;
        for (int i = lg; i < L_; i += 4) { float v = p[(size_t)i * Cc_]; s += v; s2 += v * v; }
        ps[t] = s; ps2[t] = s2; __syncthreads();
        if (t < 64) {
            float S = 0.f, S2 = 0.f;
            for (int g = 0; g < 4; g++) { S += ps[t + 64 * g]; S2 += ps2[t + 64 * g]; }
            float m = S * (1.f / L_), v = S2 * (1.f / L_) - m * m;
            float inv = rsqrtf(v + 1e-5f);
            float gg = g_c[t] * inv;
            sc[24 + t] = gg; sh[24 + t] = bc[t] - m * gg;
        }
        __syncthreads();
    }
    { // treatments, C=16, 16 l-groups
        int c = t & 15, lg = t >> 4;
        const float* p = tr + (size_t)b * L_ * Ct_ + c;
        float s = 0.f, s2 = 0.f;
        for (int i = lg; i < L_; i += 16) { float v = p[(size_t)i * Ct_]; s += v; s2 += v * v; }
        ps[t] = s; ps2[t] = s2; __syncthreads();
        if (t < 16) {
            float S = 0.f, S2 = 0.f;
            for (int g = 0; g < 16; g++) { S += ps[t + 16 * g]; S2 += ps2[t + 16 * g]; }
            float m = S * (1.f / L_), v = S2 * (1.f / L_) - m * m;
            float inv = rsqrtf(v + 1e-5f);
            float gg = g_t[t] * inv;
            sc[t] = gg; sh[t] = bt[t] - m * gg;
        }
        __syncthreads();
    }
    { // outcomes, C=8, 32 l-groups
        int c = t & 7, lg = t >> 3;
        const float* p = oc + (size_t)b * L_ * Co_ + c;
        float s = 0.f, s2 = 0.f;
        for (int i = lg; i < L_; i += 32) { float v = p[(size_t)i * Co_]; s += v; s2 += v * v; }
        ps[t] = s; ps2[t] = s2; __syncthreads();
        if (t < 8) {
            float S = 0.f, S2 = 0.f;
            for (int g = 0; g < 32; g++) { S += ps[t + 8 * g]; S2 += ps2[t + 8 * g]; }
            float m = S * (1.f / L_), v = S2 * (1.f / L_) - m * m;
            float inv = rsqrtf(v + 1e-5f);
            float gg = g_o[t] * inv;
            sc[16 + t] = gg; sh[16 + t] = bo[t] - m * gg;
        }
        __syncthreads();
    }
    // phase B: normalize + concat + pad, write f16
    f16* outp = inpH + (size_t)b * L_ * KP;
    for (int idx = t; idx < L_ * KP; idx += 256) {
        int l = idx / KP, cc = idx % KP;
        float y = 0.f;
        if (cc < 88) {
            float x;
            if (cc < 16)      x = tr[((size_t)b * L_ + l) * Ct_ + cc];
            else if (cc < 24) x = oc[((size_t)b * L_ + l) * Co_ + (cc - 16)];
            else              x = cov[((size_t)b * L_ + l) * Cc_ + (cc - 24)];
            y = x * sc[cc] + sh[cc];
        }
        outp[idx] = (f16)y;
    }
}

// ---------------- K2: gi = inp @ W_ih^T + b_ih, f16 MFMA, output f16 (M x 384) ----------
__global__ __launch_bounds__(256) void k_gemm(
        const f16* __restrict__ A, const f16* __restrict__ W,
        const float* __restrict__ bih, f16* __restrict__ gi) {
    int lane = threadIdx.x & 63, wave = threadIdx.x >> 6;
    int m0 = blockIdx.x * 64 + wave * 16;
    int r = lane & 15, q = lane >> 4;

    const f16* ap = A + (size_t)(m0 + r) * KP + q * 8;
    f16x8 a0 = *(const f16x8*)(ap);
    f16x8 a1 = *(const f16x8*)(ap + 32);
    f16x8 a2 = *(const f16x8*)(ap + 64);

    for (int n0 = 0; n0 < 24; n0++) {
        const f16* bp = W + (size_t)(n0 * 16 + r) * KP + q * 8;
        f16x8 b0 = *(const f16x8*)(bp);
        f16x8 b1 = *(const f16x8*)(bp + 32);
        f16x8 b2 = *(const f16x8*)(bp + 64);
        f32x4 acc = {0.f, 0.f, 0.f, 0.f};
        acc = __builtin_amdgcn_mfma_f32_16x16x32_f16(a0, b0, acc, 0, 0, 0);
        acc = __builtin_amdgcn_mfma_f32_16x16x32_f16(a1, b1, acc, 0, 0, 0);
        acc = __builtin_amdgcn_mfma_f32_16x16x32_f16(a2, b2, acc, 0, 0, 0);
        int n = n0 * 16 + r;
        float bias = bih[n];
        f16* gp = gi + (size_t)(m0 + q * 4) * G3 + n;
        #pragma unroll
        for (int e = 0; e < 4; e++)
            gp[(size_t)e * G3] = (f16)(acc[e] + bias);
    }
}

// ---------------- K3: GRU scan via MFMA. One block = 16 batch rows, 8 waves. -----------
// gh(16 units x 16 rows per tile) = mfma(A = W_hh rows (f16, persistent in regs),
//                                        B = h columns from LDS).
// D layout: col(lane&15) = batch row, row((lane>>4)*4+e) = hidden unit.
// Gate combine is in-register (r/z/n accs share lane/reg slots). LDS holds only h
// (16x128 f16, XOR-swizzled, double-buffered) -> 4 ds_read_b128 + 1 ds_write_b64
// per lane per step. One barrier per step.
__global__ __launch_bounds__(512, 2) void k_scan_mfma(
        const f16* __restrict__ gi, const float* __restrict__ Whh, const float* __restrict__ bhh,
        float* __restrict__ outA, float* __restrict__ outB, int rowBase) {
    const int t = threadIdx.x;
    const int w = t >> 6;          // wave 0..7: owns hidden units [16w, 16w+16)
    const int lane = t & 63;
    const int c = lane & 15;       // batch row within tile
    const int q = lane >> 4;       // 0..3
    const int lrow = blockIdx.x * R_ + c;       // local batch row (gi index)
    const int row  = rowBase + lrow;            // global batch row (output index)
    const int uD = 16 * w + q * 4;              // this lane's unit base in D

    __shared__ f16 hb[2][R_ * H_];              // 2 x 4KB, swizzled [b][k^((b&7)<<3)]

    // persistent W_hh A-fragments: unit = 16w + c, k = q*8 + 32ks + j  (f32 -> f16)
    f16x8 WA[3][4];
    #pragma unroll
    for (int g = 0; g < 3; g++)
        #pragma unroll
        for (int ks = 0; ks < 4; ks++) {
            const float* wp = Whh + (size_t)(g * H_ + 16 * w + c) * H_ + q * 8 + 32 * ks;
            f16x8 v;
            #pragma unroll
            for (int j = 0; j < 8; j++) v[j] = (f16)wp[j];
            WA[g][ks] = v;
        }
    float bR[4], bZ[4], bN[4];
    #pragma unroll
    for (int e = 0; e < 4; e++) {
        bR[e] = bhh[0 * H_ + uD + e];
        bZ[e] = bhh[1 * H_ + uD + e];
        bN[e] = bhh[2 * H_ + uD + e];
    }

    for (int i = t; i < R_ * H_; i += 512) hb[0][i] = (f16)0.f;
    float hprev[4] = {0.f, 0.f, 0.f, 0.f};

    const f16* gp = gi + (size_t)lrow * L_ * G3;
    f16x4 gR = *(const f16x4*)(gp + 0 * H_ + uD);
    f16x4 gZ = *(const f16x4*)(gp + 1 * H_ + uD);
    f16x4 gN = *(const f16x4*)(gp + 2 * H_ + uD);

    const int swzm = (c & 7) << 3;              // XOR swizzle mask (f16 index bits 3..5)
    __syncthreads();

    for (int l = 0; l < L_; l++) {
        // B-fragments of h from LDS: b = c, k = q*8 + 32ks (+j)
        const f16* hcur = hb[l & 1];
        f16x8 hB[4];
        #pragma unroll
        for (int ks = 0; ks < 4; ks++) {
            int k0 = q * 8 + 32 * ks;
            hB[ks] = *(const f16x8*)(hcur + c * H_ + (k0 ^ swzm));
        }
        f32x4 aR = {0.f,0.f,0.f,0.f}, aZ = {0.f,0.f,0.f,0.f}, aN = {0.f,0.f,0.f,0.f};
        #pragma unroll
        for (int ks = 0; ks < 4; ks++) {
            aR = __builtin_amdgcn_mfma_f32_16x16x32_f16(WA[0][ks], hB[ks], aR, 0, 0, 0);
            aZ = __builtin_amdgcn_mfma_f32_16x16x32_f16(WA[1][ks], hB[ks], aZ, 0, 0, 0);
            aN = __builtin_amdgcn_mfma_f32_16x16x32_f16(WA[2][ks], hB[ks], aN, 0, 0, 0);
        }
        // gates, in-register
        float hnew[4];
        #pragma unroll
        for (int e = 0; e < 4; e++) {
            float rg = 1.f / (1.f + __expf(-(aR[e] + bR[e] + (float)gR[e])));
            float zg = 1.f / (1.f + __expf(-(aZ[e] + bZ[e] + (float)gZ[e])));
            float pre = (float)gN[e] + rg * (aN[e] + bN[e]);
            float ee = __expf(-2.f * pre);
            float ng = 2.f / (1.f + ee) - 1.f;   // tanh, saturation-safe
            hnew[e] = (1.f - zg) * ng + zg * hprev[e];
            hprev[e] = hnew[e];
        }
        // h -> LDS (next buffer), f16
        {
            f16* hn = hb[(l + 1) & 1];
            f16x4 hv = {(f16)hnew[0], (f16)hnew[1], (f16)hnew[2], (f16)hnew[3]};
            *(f16x4*)(hn + c * H_ + (uD ^ swzm)) = hv;
        }
        // outputs (f32): units uD..uD+3 for batch row `row`
        {
            size_t o = (size_t)row * L_ + l;
            f32x4 hv = {hnew[0], hnew[1], hnew[2], hnew[3]};
            if (uD < Co_) *(f32x4*)(outA + o * Co_ + uD) = hv;
            else          *(f32x4*)(outB + o * (H_ - Co_) + (uD - Co_)) = hv;
        }
        // prefetch next step's gi
        if (l + 1 < L_) {
            const f16* gn = gp + (size_t)(l + 1) * G3;
            gR = *(const f16x4*)(gn + 0 * H_ + uD);
            gZ = *(const f16x4*)(gn + 1 * H_ + uD);
            gN = *(const f16x4*)(gn + 2 * H_ + uD);
        }
        __syncthreads();
    }
}

// ---------------- launch ----------------
extern "C" void kernel_launch(void* const* d_in, const int* in_sizes, int n_in,
                              void* d_out, int out_size, void* d_ws, size_t ws_size,
                              hipStream_t stream) {
    (void)in_sizes; (void)n_in;
    const float* cov = (const float*)d_in[0];
    const float* tr  = (const float*)d_in[1];
    const float* oc  = (const float*)d_in[2];
    const float* Wih = (const float*)d_in[3];
    const float* Whh = (const float*)d_in[4];
    const float* bih = (const float*)d_in[5];
    const float* bhh = (const float*)d_in[6];
    const float* g_t = (const float*)d_in[7];
    const float* bt  = (const float*)d_in[8];
    const float* g_o = (const float*)d_in[9];
    const float* bo  = (const float*)d_in[10];
    const float* g_c = (const float*)d_in[11];
    const float* bc  = (const float*)d_in[12];

    float* outA = (float*)d_out;
    float* outB = (float*)d_out + (size_t)B_ * L_ * Co_;

    // workspace layout: [WihH f16 384x96 | pad to 128KB | giH f16 (M_split x 384)]
    f16* WihH = (f16*)d_ws;
    f16* giH  = (f16*)((char*)d_ws + 131072);

    // normalized f16 input lives at the TOP of d_out (dead before outputs reach it)
    size_t outBytes = (size_t)out_size * 4;
    size_t ihBytes  = (size_t)B_ * L_ * KP * 2;   // 50.3 MB
    f16* inpH = (f16*)((char*)d_out + (outBytes - ihBytes));

    // pick batch split so gi fits in ws
    int S = 8;
    const int cand[4] = {1, 2, 4, 8};
    for (int i = 0; i < 4; i++) {
        size_t need = 131072 + ((size_t)B_ / cand[i]) * L_ * G3 * 2;
        if (need <= ws_size) { S = cand[i]; break; }
    }
    int Bs = B_ / S;

    k_prep_wih<<<dim3(144), dim3(256), 0, stream>>>(Wih, WihH);
    k_norm<<<dim3(B_), dim3(256), 0, stream>>>(cov, tr, oc, g_t, bt, g_o, bo, g_c, bc, inpH);

    for (int s = 0; s < S; s++) {
        const f16* Asub = inpH + (size_t)s * Bs * L_ * KP;
        int Msub = Bs * L_;
        k_gemm<<<dim3(Msub / 64), dim3(256), 0, stream>>>(Asub, WihH, bih, giH);
        k_scan_mfma<<<dim3(Bs / R_), dim3(512), 0, stream>>>(giH, Whh, bhh, outA, outB, s * Bs);
    }
}